// Round 1
// baseline (238.894 us; speedup 1.0000x reference)
//
#include <hip/hip_runtime.h>

// Trilinear resample of a (B=4, D=64, H=64, W=64, C=32) fp32 volume.
// Identity affine => sample coord along each spatial axis is p * 62/63.
// Each thread: one float4 (4 channels) of one output voxel.
// tid = voxel*8 + channel_quad  => wave (64 lanes) = 8 consecutive voxels
// along W x 32 channels = 1 KiB contiguous store; corner gathers are
// near-contiguous (x0 advances ~1 per voxel). Memory-bound.

#define BD 4
#define DD 64
#define HH 64
#define WW 64
#define CC 32
#define C4 (CC / 4)   // float4 quads per voxel = 8

__global__ __launch_bounds__(256) void trilerp_kernel(
    const float4* __restrict__ in, float4* __restrict__ out) {
    int t = blockIdx.x * blockDim.x + threadIdx.x;

    int cq  = t & (C4 - 1);
    int vox = t >> 3;
    int k = vox & 63;          // width index
    int j = (vox >> 6) & 63;   // height index
    int i = (vox >> 12) & 63;  // depth index
    int b = vox >> 18;         // batch

    const float s = 62.0f / 63.0f;
    float xs = (float)k * s;
    float ys = (float)j * s;
    float zs = (float)i * s;

    int x0 = (int)xs;          // coords are >= 0, cast == floor
    int y0 = (int)ys;
    int z0 = (int)zs;
    float fx = xs - (float)x0;
    float fy = ys - (float)y0;
    float fz = zs - (float)z0;
    int x1 = min(x0 + 1, WW - 1);
    int y1 = min(y0 + 1, HH - 1);
    int z1 = min(z0 + 1, DD - 1);

    // float4-granular offsets: voxel (b,z,y,x) channel-quad cq
    //   = (((b*64 + z)*64 + y)*64 + x)*8 + cq
    int bb  = b << 21;
    int z0o = bb + (z0 << 15);
    int z1o = bb + (z1 << 15);
    int y0o = y0 << 9;
    int y1o = y1 << 9;
    int x0o = (x0 << 3) + cq;
    int x1o = (x1 << 3) + cq;

    float4 v000 = in[z0o + y0o + x0o];  // (z0,y0,x0)
    float4 v010 = in[z0o + y1o + x0o];  // (z0,y1,x0)
    float4 v001 = in[z0o + y0o + x1o];  // (z0,y0,x1)
    float4 v011 = in[z0o + y1o + x1o];  // (z0,y1,x1)
    float4 v100 = in[z1o + y0o + x0o];  // (z1,y0,x0)
    float4 v110 = in[z1o + y1o + x0o];  // (z1,y1,x0)
    float4 v101 = in[z1o + y0o + x1o];  // (z1,y0,x1)
    float4 v111 = in[z1o + y1o + x1o];  // (z1,y1,x1)

    float gx = 1.0f - fx, gy = 1.0f - fy, gz = 1.0f - fz;
    float wa = gx * gy * gz;  // x0 y0 z0
    float wb = gx * fy * gz;  // x0 y1 z0
    float wc = fx * gy * gz;  // x1 y0 z0
    float wd = fx * fy * gz;  // x1 y1 z0
    float we = gx * gy * fz;  // x0 y0 z1
    float wf = gx * fy * fz;  // x0 y1 z1
    float wg = fx * gy * fz;  // x1 y0 z1
    float wh = fx * fy * fz;  // x1 y1 z1

    float4 r;
    r.x = fmaf(v000.x, wa, fmaf(v010.x, wb, fmaf(v001.x, wc, fmaf(v011.x, wd,
          fmaf(v100.x, we, fmaf(v110.x, wf, fmaf(v101.x, wg, v111.x * wh)))))));
    r.y = fmaf(v000.y, wa, fmaf(v010.y, wb, fmaf(v001.y, wc, fmaf(v011.y, wd,
          fmaf(v100.y, we, fmaf(v110.y, wf, fmaf(v101.y, wg, v111.y * wh)))))));
    r.z = fmaf(v000.z, wa, fmaf(v010.z, wb, fmaf(v001.z, wc, fmaf(v011.z, wd,
          fmaf(v100.z, we, fmaf(v110.z, wf, fmaf(v101.z, wg, v111.z * wh)))))));
    r.w = fmaf(v000.w, wa, fmaf(v010.w, wb, fmaf(v001.w, wc, fmaf(v011.w, wd,
          fmaf(v100.w, we, fmaf(v110.w, wf, fmaf(v101.w, wg, v111.w * wh)))))));

    out[t] = r;
}

extern "C" void kernel_launch(void* const* d_in, const int* in_sizes, int n_in,
                              void* d_out, int out_size, void* d_ws, size_t ws_size,
                              hipStream_t stream) {
    const float4* in = (const float4*)d_in[0];
    float4* out = (float4*)d_out;

    const int total = BD * DD * HH * WW * C4;  // 8,388,608 float4 threads
    const int block = 256;
    const int grid = total / block;            // 32,768 blocks

    trilerp_kernel<<<grid, block, 0, stream>>>(in, out);
}